// Round 5
// baseline (319.717 us; speedup 1.0000x reference)
//
#include <hip/hip_runtime.h>
#include <stdint.h>

#define N_NODES 100000
#define N_EDGES 640000
#define HIDDEN  128
#define EPS     1e-6f

// ---------------------------------------------------------------------------
// MEASUREMENT ROUND. Structure = round-0 (158.4 us verified), but each phase
// is REP-inflated with semantics-preserving repetition so every kernel rises
// above the ~40 us harness fills and appears in the rocprof top-5 with its
// own counter row. Opaque-pointer asm per rep defeats CSE/licm so loads,
// compute AND stores genuinely repeat (guide rule #17). The real edge kernel
// (atomics) runs exactly once -> output identical to round 0.
// ---------------------------------------------------------------------------
#define REP_P 16   // precompute
#define REP_D 5    // node dots
#define REP_E 16   // edge probe (no atomics)
#define REP_F 5    // final

#define OPAQUE_PTR(T, name, src)            \
    uintptr_t name##_u = (uintptr_t)(src);  \
    asm volatile("" : "+v"(name##_u));      \
    T name = (T)name##_u;

// ---------------------------------------------------------------------------
// Kernel 0: u[k], v[k], c  (round-0 body, REP_P reps)
// ---------------------------------------------------------------------------
__global__ void precompute_uvc(const float* __restrict__ W_,
                               const float* __restrict__ b_,
                               const float* __restrict__ att_w_,
                               float* __restrict__ u_,
                               float* __restrict__ v_,
                               float* __restrict__ c_) {
    __shared__ float su_s[4][HIDDEN];
    __shared__ float sv_s[4][HIDDEN];
    const int k     = threadIdx.x & 127;
    const int chunk = threadIdx.x >> 7;   // 0..3

    #pragma unroll 1
    for (int rep = 0; rep < REP_P; ++rep) {
        OPAQUE_PTR(const float*, W, W_)
        OPAQUE_PTR(const float*, b, b_)
        OPAQUE_PTR(const float*, att_w, att_w_)
        OPAQUE_PTR(float*, u, u_)
        OPAQUE_PTR(float*, v, v_)
        OPAQUE_PTR(float*, c, c_)

        float su = 0.f, sv = 0.f;
        #pragma unroll
        for (int jj = 0; jj < 32; ++jj) {
            int j = chunk * 32 + jj;
            float w = W[j * HIDDEN + k];
            su += att_w[j] * w;
            sv += att_w[HIDDEN + j] * w;
        }
        su_s[chunk][k] = su;
        sv_s[chunk][k] = sv;

        if (threadIdx.x < 64) {
            int t0 = threadIdx.x, t1 = threadIdx.x + 64;
            float t = att_w[t0] * b[t0] + att_w[HIDDEN + t0] * b[t0]
                    + att_w[t1] * b[t1] + att_w[HIDDEN + t1] * b[t1];
            #pragma unroll
            for (int off = 32; off > 0; off >>= 1) t += __shfl_xor(t, off);
            if (threadIdx.x == 0) *c = t;
        }

        __syncthreads();
        if (chunk == 0) {
            u[k] = su_s[0][k] + su_s[1][k] + su_s[2][k] + su_s[3][k];
            v[k] = sv_s[0][k] + sv_s[1][k] + sv_s[2][k] + sv_s[3][k];
        }
        __syncthreads();   // WAR guard before next rep overwrites LDS
    }
}

// ---------------------------------------------------------------------------
// Kernel 1: p_i = u.x_i, q_i = v.x_i, nacc_i = 0  (round-0 body, REP_D reps)
// ---------------------------------------------------------------------------
__global__ __launch_bounds__(256) void node_dots(
    const float* __restrict__ x_,
    const float* __restrict__ u_,
    const float* __restrict__ v_,
    float* __restrict__ p_,
    float* __restrict__ q_,
    float* __restrict__ nacc_) {
    int gid  = blockIdx.x * blockDim.x + threadIdx.x;
    int wave = gid >> 6;
    int lane = threadIdx.x & 63;
    int half = lane >> 5;
    int sub  = lane & 31;
    int node = wave * 2 + half;
    if (node >= N_NODES) return;

    #pragma unroll 1
    for (int rep = 0; rep < REP_D; ++rep) {
        OPAQUE_PTR(const float*, x, x_)
        OPAQUE_PTR(const float*, u, u_)
        OPAQUE_PTR(const float*, v, v_)
        OPAQUE_PTR(float*, p, p_)
        OPAQUE_PTR(float*, q, q_)
        OPAQUE_PTR(float*, nacc, nacc_)

        float4 xv = ((const float4*)(x + (size_t)node * HIDDEN))[sub];
        float4 uv = ((const float4*)u)[sub];
        float4 vv = ((const float4*)v)[sub];

        float sp = xv.x * uv.x + xv.y * uv.y + xv.z * uv.z + xv.w * uv.w;
        float sq = xv.x * vv.x + xv.y * vv.y + xv.z * vv.z + xv.w * vv.w;
        #pragma unroll
        for (int off = 16; off > 0; off >>= 1) {
            sp += __shfl_xor(sp, off);
            sq += __shfl_xor(sq, off);
        }
        if (sub == 0) {
            p[node]    = sp;
            q[node]    = sq;
            nacc[node] = 0.f;
        }
    }
}

// ---------------------------------------------------------------------------
// Kernel 2a: edge PROBE — identical loads + exp as the real edge kernel, but
// NO atomics and NO stores (asm keep-alive). REP_E reps. Separates edge
// memory/VALU cost from atomic cost in the counter rows.
// ---------------------------------------------------------------------------
__global__ __launch_bounds__(256) void edge_probe(
    const int*   __restrict__ e_,
    const float* __restrict__ p_,
    const float* __restrict__ q_,
    const float* __restrict__ c_) {
    int eid = blockIdx.x * blockDim.x + threadIdx.x;
    if (eid >= N_EDGES) return;
    float acc = 0.f;
    #pragma unroll 1
    for (int rep = 0; rep < REP_E; ++rep) {
        OPAQUE_PTR(const int*,   e, e_)
        OPAQUE_PTR(const float*, p, p_)
        OPAQUE_PTR(const float*, q, q_)
        OPAQUE_PTR(const float*, c, c_)
        int2 ed = ((const int2*)e)[eid];
        float score = p[ed.x] + q[ed.y] + c[0];
        float lr = score > 0.f ? score : 0.2f * score;
        acc += expf(lr);
    }
    asm volatile("" :: "v"(acc));   // keep alive, no store
}

// ---------------------------------------------------------------------------
// Kernel 2b: REAL edge kernel — round-0 body, runs exactly once.
// ---------------------------------------------------------------------------
__global__ __launch_bounds__(256) void edge_kernel(
    const int*   __restrict__ e,
    const float* __restrict__ p,
    const float* __restrict__ q,
    const float* __restrict__ c,
    float* __restrict__ nacc) {
    int eid = blockIdx.x * blockDim.x + threadIdx.x;
    if (eid >= N_EDGES) return;
    int2 ed = ((const int2*)e)[eid];
    float score = p[ed.x] + q[ed.y] + c[0];
    float lr = score > 0.f ? score : 0.2f * score;
    atomicAdd(&nacc[ed.y], expf(lr));
}

// ---------------------------------------------------------------------------
// Kernel 3: final — round-0 body, REP_F reps (idempotent).
// ---------------------------------------------------------------------------
__global__ __launch_bounds__(256) void final_kernel(
    const float* __restrict__ x_,
    const float* __restrict__ nacc_,
    const float* __restrict__ norm_w_,
    const float* __restrict__ norm_b_,
    float* __restrict__ out_) {
    int gid  = blockIdx.x * blockDim.x + threadIdx.x;
    int wave = gid >> 6;
    int lane = threadIdx.x & 63;
    int half = lane >> 5;
    int sub  = lane & 31;
    int node = wave * 2 + half;
    if (node >= N_NODES) return;

    #pragma unroll 1
    for (int rep = 0; rep < REP_F; ++rep) {
        OPAQUE_PTR(const float*, x, x_)
        OPAQUE_PTR(const float*, nacc, nacc_)
        OPAQUE_PTR(const float*, norm_w, norm_w_)
        OPAQUE_PTR(const float*, norm_b, norm_b_)
        OPAQUE_PTR(float*, out, out_)

        float nn = nacc[node];
        float inv_n = 1.f / (nn == 0.f ? 1.f : nn);

        float4 xv = ((const float4*)(x + (size_t)node * HIDDEN))[sub];
        float4 y;
        {
            float h;
            h = xv.x * inv_n; h = h > 0.f ? h : 0.f; y.x = h + xv.x;
            h = xv.y * inv_n; h = h > 0.f ? h : 0.f; y.y = h + xv.y;
            h = xv.z * inv_n; h = h > 0.f ? h : 0.f; y.z = h + xv.z;
            h = xv.w * inv_n; h = h > 0.f ? h : 0.f; y.w = h + xv.w;
        }

        float ss = y.x * y.x + y.y * y.y + y.z * y.z + y.w * y.w;
        #pragma unroll
        for (int off = 16; off > 0; off >>= 1) ss += __shfl_xor(ss, off);
        float inv_rms = rsqrtf(ss * (1.f / HIDDEN) + EPS);

        float4 wv = ((const float4*)norm_w)[sub];
        float4 bv = ((const float4*)norm_b)[sub];
        float4 ov;
        ov.x = wv.x * (y.x * inv_rms) + bv.x;
        ov.y = wv.y * (y.y * inv_rms) + bv.y;
        ov.z = wv.z * (y.z * inv_rms) + bv.z;
        ov.w = wv.w * (y.w * inv_rms) + bv.w;
        ((float4*)(out + (size_t)node * HIDDEN))[sub] = ov;
    }
}

extern "C" void kernel_launch(void* const* d_in, const int* in_sizes, int n_in,
                              void* d_out, int out_size, void* d_ws, size_t ws_size,
                              hipStream_t stream) {
    const float* x      = (const float*)d_in[0];
    const float* W      = (const float*)d_in[1];
    const float* b      = (const float*)d_in[2];
    const float* att_w  = (const float*)d_in[3];
    const float* norm_w = (const float*)d_in[4];
    const float* norm_b = (const float*)d_in[5];
    const int*   e      = (const int*)d_in[6];
    float* out = (float*)d_out;

    // workspace layout (floats): u[128] v[128] c[1] pad | p[N] q[N] nacc[N]
    float* ws = (float*)d_ws;
    float* u    = ws;
    float* v    = ws + 128;
    float* c    = ws + 256;
    float* p    = ws + 1024;
    float* q    = p + N_NODES;
    float* nacc = q + N_NODES;

    precompute_uvc<<<1, 512, 0, stream>>>(W, b, att_w, u, v, c);

    {   // 2 nodes/wave, 4 waves/block -> 8 nodes/block
        int blocks = (N_NODES + 7) / 8;
        node_dots<<<blocks, 256, 0, stream>>>(x, u, v, p, q, nacc);
    }
    {
        int blocks = (N_EDGES + 255) / 256;
        edge_probe<<<blocks, 256, 0, stream>>>(e, p, q, c);
        edge_kernel<<<blocks, 256, 0, stream>>>(e, p, q, c, nacc);
    }
    {
        int blocks = (N_NODES + 7) / 8;
        final_kernel<<<blocks, 256, 0, stream>>>(x, nacc, norm_w, norm_b, out);
    }
}

// Round 6
// 159.873 us; speedup vs baseline: 1.9998x; 1.9998x over previous
//
#include <hip/hip_runtime.h>

#define N_NODES 100000
#define N_EDGES 640000
#define HIDDEN  128
#define EPS     1e-6f

// ---------------------------------------------------------------------------
// Kernel 0: u[k] = sum_j att_w[j]*W[j,k];  v[k] = sum_j att_w[128+j]*W[j,k];
//           c = att_w[0:128].b + att_w[128:256].b
// 4 blocks x 128 threads, split by k-columns: each block cold-fetches only
// 16 KB of W (vs 64 KB on one CU in the 1-block version) -> ~4x the fetch
// parallelism on the critical path. Within a block: 4 j-chunks x 32 cols,
// LDS reduce. c on block 0's first wave (independent of the main loop).
// ---------------------------------------------------------------------------
__global__ void precompute_uvc(const float* __restrict__ W,
                               const float* __restrict__ b,
                               const float* __restrict__ att_w,
                               float* __restrict__ u,
                               float* __restrict__ v,
                               float* __restrict__ c) {
    __shared__ float su_s[4][32];
    __shared__ float sv_s[4][32];
    const int kb    = blockIdx.x;          // 0..3: which 32-column slice
    const int kl    = threadIdx.x & 31;    // column within slice
    const int chunk = threadIdx.x >> 5;    // 0..3: which 32-row j-chunk
    const int k     = kb * 32 + kl;

    float su = 0.f, sv = 0.f;
    #pragma unroll
    for (int jj = 0; jj < 32; ++jj) {
        int j = chunk * 32 + jj;           // wave-uniform -> att_w via s_load
        float w = W[j * HIDDEN + k];       // 128B contiguous per 32-lane group
        su += att_w[j] * w;
        sv += att_w[HIDDEN + j] * w;
    }
    su_s[chunk][kl] = su;
    sv_s[chunk][kl] = sv;

    // c: block 0, wave 0 — fully parallel with the loop above (no LDS dep)
    if (kb == 0 && threadIdx.x < 64) {
        int t0 = threadIdx.x, t1 = threadIdx.x + 64;
        float t = (att_w[t0] + att_w[HIDDEN + t0]) * b[t0]
                + (att_w[t1] + att_w[HIDDEN + t1]) * b[t1];
        #pragma unroll
        for (int off = 32; off > 0; off >>= 1) t += __shfl_xor(t, off);
        if (threadIdx.x == 0) *c = t;
    }

    __syncthreads();
    if (chunk == 0) {
        u[k] = su_s[0][kl] + su_s[1][kl] + su_s[2][kl] + su_s[3][kl];
        v[k] = sv_s[0][kl] + sv_s[1][kl] + sv_s[2][kl] + sv_s[3][kl];
    }
}

// ---------------------------------------------------------------------------
// Kernel 1: p_i = u.x_i, q_i = v.x_i, and nacc_i = 0.
// float4 per lane; 32 lanes cover one 128-float row -> 2 nodes per wave,
// wave reads 1 KiB contiguous. Reduce within 32-lane halves via shfl_xor.
// (warm-measured ~6 us: at the 51 MB cold-x HBM floor — unchanged from R0)
// ---------------------------------------------------------------------------
__global__ __launch_bounds__(256) void node_dots(
    const float* __restrict__ x,
    const float* __restrict__ u,
    const float* __restrict__ v,
    float* __restrict__ p,
    float* __restrict__ q,
    float* __restrict__ nacc) {
    int gid  = blockIdx.x * blockDim.x + threadIdx.x;
    int wave = gid >> 6;
    int lane = threadIdx.x & 63;
    int half = lane >> 5;         // 0 or 1
    int sub  = lane & 31;         // element group within row
    int node = wave * 2 + half;
    if (node >= N_NODES) return;

    float4 xv = ((const float4*)(x + (size_t)node * HIDDEN))[sub];
    float4 uv = ((const float4*)u)[sub];
    float4 vv = ((const float4*)v)[sub];

    float sp = xv.x * uv.x + xv.y * uv.y + xv.z * uv.z + xv.w * uv.w;
    float sq = xv.x * vv.x + xv.y * vv.y + xv.z * vv.z + xv.w * vv.w;
    #pragma unroll
    for (int off = 16; off > 0; off >>= 1) {
        sp += __shfl_xor(sp, off);
        sq += __shfl_xor(sq, off);
    }
    if (sub == 0) {
        p[node]    = sp;
        q[node]    = sq;
        nacc[node] = 0.f;        // replaces a separate memset dispatch
    }
}

// ---------------------------------------------------------------------------
// Kernel 2: a = exp(leaky_relu(p[src]+q[dst]+c)); atomicAdd into nacc[dst].
// 2 edges per thread via int4: 16B/lane coalesced edge reads, 4 L2 gathers
// in flight per thread (R5 probe: phase is gather-latency-bound, VALUBusy
// 8.5%, HBM 0.8% -> per-thread MLP is the only lever).
// ---------------------------------------------------------------------------
__global__ __launch_bounds__(256) void edge_kernel(
    const int*   __restrict__ e,
    const float* __restrict__ p,
    const float* __restrict__ q,
    const float* __restrict__ c,
    float* __restrict__ nacc) {
    int i = blockIdx.x * blockDim.x + threadIdx.x;
    if (i >= N_EDGES / 2) return;
    const float cc = c[0];
    int4 ed = ((const int4*)e)[i];          // (src0,dst0,src1,dst1)
    float s0 = p[ed.x] + q[ed.y] + cc;
    float s1 = p[ed.z] + q[ed.w] + cc;
    s0 = s0 > 0.f ? s0 : 0.2f * s0;
    s1 = s1 > 0.f ? s1 : 0.2f * s1;
    atomicAdd(&nacc[ed.y], expf(s0));
    atomicAdd(&nacc[ed.w], expf(s1));
}

// ---------------------------------------------------------------------------
// Kernel 3: y = relu(x/n') + x ; out = norm_w * y * rsqrt(mean(y^2)+eps) + norm_b
// Same 2-nodes-per-wave float4 layout as node_dots. x is L3-warm from K1;
// the 51 MB out-write is the HBM floor here.
// ---------------------------------------------------------------------------
__global__ __launch_bounds__(256) void final_kernel(
    const float* __restrict__ x,
    const float* __restrict__ nacc,
    const float* __restrict__ norm_w,
    const float* __restrict__ norm_b,
    float* __restrict__ out) {
    int gid  = blockIdx.x * blockDim.x + threadIdx.x;
    int wave = gid >> 6;
    int lane = threadIdx.x & 63;
    int half = lane >> 5;
    int sub  = lane & 31;
    int node = wave * 2 + half;
    if (node >= N_NODES) return;

    float nn = nacc[node];
    float inv_n = 1.f / (nn == 0.f ? 1.f : nn);

    float4 xv = ((const float4*)(x + (size_t)node * HIDDEN))[sub];
    float4 y;
    {
        float h;
        h = xv.x * inv_n; h = h > 0.f ? h : 0.f; y.x = h + xv.x;
        h = xv.y * inv_n; h = h > 0.f ? h : 0.f; y.y = h + xv.y;
        h = xv.z * inv_n; h = h > 0.f ? h : 0.f; y.z = h + xv.z;
        h = xv.w * inv_n; h = h > 0.f ? h : 0.f; y.w = h + xv.w;
    }

    float ss = y.x * y.x + y.y * y.y + y.z * y.z + y.w * y.w;
    #pragma unroll
    for (int off = 16; off > 0; off >>= 1) ss += __shfl_xor(ss, off);
    float inv_rms = rsqrtf(ss * (1.f / HIDDEN) + EPS);

    float4 wv = ((const float4*)norm_w)[sub];
    float4 bv = ((const float4*)norm_b)[sub];
    float4 ov;
    ov.x = wv.x * (y.x * inv_rms) + bv.x;
    ov.y = wv.y * (y.y * inv_rms) + bv.y;
    ov.z = wv.z * (y.z * inv_rms) + bv.z;
    ov.w = wv.w * (y.w * inv_rms) + bv.w;
    ((float4*)(out + (size_t)node * HIDDEN))[sub] = ov;
}

extern "C" void kernel_launch(void* const* d_in, const int* in_sizes, int n_in,
                              void* d_out, int out_size, void* d_ws, size_t ws_size,
                              hipStream_t stream) {
    const float* x      = (const float*)d_in[0];
    const float* W      = (const float*)d_in[1];
    const float* b      = (const float*)d_in[2];
    const float* att_w  = (const float*)d_in[3];
    const float* norm_w = (const float*)d_in[4];
    const float* norm_b = (const float*)d_in[5];
    const int*   e      = (const int*)d_in[6];
    float* out = (float*)d_out;

    // workspace layout (floats): u[128] v[128] c[1] pad | p[N] q[N] nacc[N]
    float* ws = (float*)d_ws;
    float* u    = ws;
    float* v    = ws + 128;
    float* c    = ws + 256;
    float* p    = ws + 1024;
    float* q    = p + N_NODES;
    float* nacc = q + N_NODES;

    precompute_uvc<<<4, 128, 0, stream>>>(W, b, att_w, u, v, c);

    {   // 2 nodes/wave, 4 waves/block -> 8 nodes/block
        int blocks = (N_NODES + 7) / 8;
        node_dots<<<blocks, 256, 0, stream>>>(x, u, v, p, q, nacc);
    }
    {
        int blocks = (N_EDGES / 2 + 255) / 256;
        edge_kernel<<<blocks, 256, 0, stream>>>(e, p, q, c, nacc);
    }
    {
        int blocks = (N_NODES + 7) / 8;
        final_kernel<<<blocks, 256, 0, stream>>>(x, nacc, norm_w, norm_b, out);
    }
}